// Round 2
// baseline (1739.684 us; speedup 1.0000x reference)
//
#include <hip/hip_runtime.h>
#include <hip/hip_fp16.h>

typedef _Float16 f16;
typedef _Float16 f16x2 __attribute__((ext_vector_type(2)));
typedef _Float16 f16x8 __attribute__((ext_vector_type(8)));
typedef float    f32x4 __attribute__((ext_vector_type(4)));
typedef unsigned int u32;
typedef unsigned long long u64;

#define BN_EPS 1e-5f

static constexpr int BB  = 32;    // batch
static constexpr int CC  = 128;   // channels
static constexpr int HWN = 1024;  // H*W = L
static constexpr int RIN = 256;
static constexpr int RH  = 512;
static constexpr int OCN = 128;

// ---------------------------------------------------------------- BN stats
__global__ void bn_stats_kernel(const float* __restrict__ x,
                                const float* __restrict__ gamma,
                                const float* __restrict__ beta,
                                float* __restrict__ scale,
                                float* __restrict__ shift) {
    int c = blockIdx.x;
    int tid = threadIdx.x;
    float s = 0.f, s2 = 0.f;
    const float* xc = x + (size_t)c * HWN;
    for (int idx = tid; idx < BB * HWN; idx += 256) {
        int b = idx >> 10, hw = idx & 1023;
        float v = xc[(size_t)b * (CC * HWN) + hw];
        s += v; s2 += v * v;
    }
    for (int off = 32; off > 0; off >>= 1) {
        s  += __shfl_down(s, off, 64);
        s2 += __shfl_down(s2, off, 64);
    }
    __shared__ float ls[4], ls2[4];
    int wv = tid >> 6, ln = tid & 63;
    if (ln == 0) { ls[wv] = s; ls2[wv] = s2; }
    __syncthreads();
    if (tid == 0) {
        float ts  = ls[0] + ls[1] + ls[2] + ls[3];
        float ts2 = ls2[0] + ls2[1] + ls2[2] + ls2[3];
        const float inv_n = 1.0f / (BB * HWN);
        float mean = ts * inv_n;
        float var  = ts2 * inv_n - mean * mean;
        float rstd = rsqrtf(var + BN_EPS);
        float sc = gamma[c] * rstd;
        scale[c] = sc;
        shift[c] = beta[c] - mean * sc;
    }
}

// ------------------------------------------- normalize + transpose -> A1 f16
__global__ void prep_x_kernel(const float* __restrict__ x,
                              const float* __restrict__ scale,
                              const float* __restrict__ shift,
                              f16* __restrict__ A1) {
    __shared__ float tile[32][33];
    int tx = threadIdx.x, ty = threadIdx.y;  // 32 x 8
    int hb = blockIdx.x, cb = blockIdx.y, b = blockIdx.z;
    #pragma unroll
    for (int k = 0; k < 4; k++) {
        int c  = cb * 32 + ty + 8 * k;
        int hw = hb * 32 + tx;
        tile[ty + 8 * k][tx] = x[(size_t)b * (CC * HWN) + (size_t)c * HWN + hw];
    }
    __syncthreads();
    #pragma unroll
    for (int k = 0; k < 4; k++) {
        int hw = hb * 32 + ty + 8 * k;
        int c  = cb * 32 + tx;
        float v = tile[tx][ty + 8 * k];
        A1[(size_t)(b * HWN + hw) * CC + c] = (f16)(v * scale[c] + shift[c]);
    }
}

// ------------------------------------------------------------ weight prep
__global__ void prep_w_kernel(const float* __restrict__ w_in,
                              const float* __restrict__ w_ih,
                              const float* __restrict__ w_out,
                              const float* __restrict__ w_hh,
                              const float* __restrict__ b_ih,
                              const float* __restrict__ b_hh,
                              f16* __restrict__ w_in_h,
                              f16* __restrict__ w_ih_h,
                              f16* __restrict__ w_out_h,
                              u32* __restrict__ wr,
                              float* __restrict__ bihh,
                              u64* __restrict__ comm) {
    int idx = blockIdx.x * 256 + threadIdx.x;
    if (idx < 32768) { w_in_h[idx] = (f16)w_in[idx]; return; }
    idx -= 32768;
    if (idx < 131072) { w_ih_h[idx] = (f16)w_ih[idx]; return; }
    idx -= 131072;
    if (idx < 65536) { w_out_h[idx] = (f16)w_out[idx]; return; }
    idx -= 65536;
    if (idx < 131072) {
        // word idx -> (slice s, thread t, reg k); reg k = r*16+n
        int s = idx >> 15, rem = idx & 32767;
        int t = rem >> 6, k = rem & 63;
        int r = k >> 4, n = k & 15;
        int jg = t & 31, sl = t >> 5;
        int j  = s * 128 + 4 * jg + r;       // output row
        int i2 = sl * 16 + n;                // h-pair index
        f16 lo = (f16)w_hh[(size_t)j * 512 + 2 * i2];
        f16 hi = (f16)w_hh[(size_t)j * 512 + 2 * i2 + 1];
        wr[idx] = (u32)__builtin_bit_cast(unsigned short, lo) |
                  ((u32)__builtin_bit_cast(unsigned short, hi) << 16);
        return;
    }
    idx -= 131072;
    if (idx < 512) { bihh[idx] = b_ih[idx] + b_hh[idx]; return; }
    idx -= 512;
    if (idx < 16384) comm[idx] = 0ULL;
}

// ------------------------------------------------------------- MFMA GEMM
template <int MODE>
__global__ void gemm_kernel(const f16* __restrict__ A,
                            const f16* __restrict__ W,
                            const float* __restrict__ bias,
                            void* __restrict__ outp,
                            int N, int K) {
    int wave = threadIdx.x >> 6;
    int lane = threadIdx.x & 63;
    int q = lane >> 4, r = lane & 15;
    int bm = blockIdx.x * 256 + wave * 64;
    int bn = blockIdx.y * 64;

    f32x4 acc[4][4];
    #pragma unroll
    for (int i = 0; i < 4; i++)
        #pragma unroll
        for (int j = 0; j < 4; j++)
            acc[i][j] = (f32x4){0.f, 0.f, 0.f, 0.f};

    const f16* Ap = A + (size_t)(bm + r) * K + 8 * q;
    const f16* Wp = W + (size_t)(bn + r) * K + 8 * q;

    for (int k = 0; k < K; k += 32) {
        f16x8 av[4], bv[4];
        #pragma unroll
        for (int i = 0; i < 4; i++)
            av[i] = *(const f16x8*)(Ap + (size_t)(16 * i) * K + k);
        #pragma unroll
        for (int i = 0; i < 4; i++)
            bv[i] = *(const f16x8*)(Wp + (size_t)(16 * i) * K + k);
        #pragma unroll
        for (int mi = 0; mi < 4; mi++)
            #pragma unroll
            for (int ni = 0; ni < 4; ni++)
                acc[mi][ni] = __builtin_amdgcn_mfma_f32_16x16x32_f16(
                    av[mi], bv[ni], acc[mi][ni], 0, 0, 0);
    }

    #pragma unroll
    for (int mi = 0; mi < 4; mi++) {
        #pragma unroll
        for (int ni = 0; ni < 4; ni++) {
            int col = bn + 16 * ni + r;
            float bval = bias[col];
            #pragma unroll
            for (int i = 0; i < 4; i++) {
                int row = bm + 16 * mi + 4 * q + i;
                float val = acc[mi][ni][i] + bval;
                if (MODE == 0) {
                    val = val - tanhf(val);
                    ((f16*)outp)[(size_t)row * N + col] = (f16)val;
                } else if (MODE == 1) {
                    ((f16*)outp)[(size_t)row * N + col] = (f16)val;
                } else {
                    int b = row >> 10, hw = row & 1023;
                    ((float*)outp)[(size_t)b * (OCN * HWN) + (size_t)col * HWN + hw] = val;
                }
            }
        }
    }
}

// ---------------------------------------------------------------- RNN scan
// 4 slices x 32 batches = 128 WGs (1 per CU). W_hh slice kept in registers.
// Mechanism history (rounds 3-8): local array -> SROA fails -> scratch;
// named SSA from a __restrict__ pointer -> invariant-load REMAT re-streams
// the weights from L2 every step (VGPR_Count stuck at 52, 3320 cyc/step);
// raw asm loads without early-clobber -> address clobber crash; "+v" on
// uint4 -> "tied indirect register inputs" compile error (multi-register
// tied operands unsupported). THIS round: pin at 32-bit granularity — load
// 16x dwordx4, unpack to 64 named u32, pass through 4 asm volatile
// statements with 16 single-VGPR "+v" ties each. asm volatile results
// cannot be remat'ed from memory -> 64 weight VGPRs stay live (budget 256
// via launch_bounds(512,2)). Verify via VGPR_Count >= 116.
// Cross-WG h exchange: RELAXED u64 atomics (payload+tag in one word,
// parity double-buffer); pollers on waves 4-6, finalize on waves 0-1.
__device__ __forceinline__ float dot2acc(u32 w, f16x2 h, float c) {
#if __has_builtin(__builtin_amdgcn_fdot2)
    return __builtin_amdgcn_fdot2(__builtin_bit_cast(f16x2, w), h, c, false);
#else
    f16x2 a = __builtin_bit_cast(f16x2, w);
    return c + (float)a[0] * (float)h[0] + (float)a[1] * (float)h[1];
#endif
}

#define ROW16(acc, a,b,c,d,e,f,g,h,i,j,k,l,m,n,o,p)                \
    acc = dot2acc(a, H0,  acc); acc = dot2acc(b, H1,  acc);        \
    acc = dot2acc(c, H2,  acc); acc = dot2acc(d, H3,  acc);        \
    acc = dot2acc(e, H4,  acc); acc = dot2acc(f, H5,  acc);        \
    acc = dot2acc(g, H6,  acc); acc = dot2acc(h, H7,  acc);        \
    acc = dot2acc(i, H8,  acc); acc = dot2acc(j, H9,  acc);        \
    acc = dot2acc(k, H10, acc); acc = dot2acc(l, H11, acc);        \
    acc = dot2acc(m, H12, acc); acc = dot2acc(n, H13, acc);        \
    acc = dot2acc(o, H14, acc); acc = dot2acc(p, H15, acc)

__global__ __launch_bounds__(512, 2) void rnn_kernel(const u32* WR,
                                                     f16* __restrict__ xh,
                                                     u64* comm) {
    const int wg = blockIdx.x;
    const int b  = wg & 31;   // batch  (4 slices of a batch share wg%8 -> same XCD)
    const int s  = wg >> 5;   // slice: rows [128s, 128s+128)
    const int t  = threadIdx.x;
    const int jg = t & 31;    // 4 rows: 128s + 4jg .. +3
    const int sl = t >> 5;    // 16 h-pair slices of 16 pairs

    __shared__ __align__(16) f16 hbuf[512];
    __shared__ float part[16][128];

    // this thread's 64 weight words: 16x dwordx4 -> 64 named u32 scalars.
    const uint4* wp = (const uint4*)(WR + ((size_t)(s * 512 + t) << 6));
    uint4 q0_  = wp[0],  q1_  = wp[1],  q2_  = wp[2],  q3_  = wp[3];
    uint4 q4_  = wp[4],  q5_  = wp[5],  q6_  = wp[6],  q7_  = wp[7];
    uint4 q8_  = wp[8],  q9_  = wp[9],  q10_ = wp[10], q11_ = wp[11];
    uint4 q12_ = wp[12], q13_ = wp[13], q14_ = wp[14], q15_ = wp[15];
    u32 W00 = q0_.x,  W01 = q0_.y,  W02 = q0_.z,  W03 = q0_.w;
    u32 W04 = q1_.x,  W05 = q1_.y,  W06 = q1_.z,  W07 = q1_.w;
    u32 W08 = q2_.x,  W09 = q2_.y,  W10 = q2_.z,  W11 = q2_.w;
    u32 W12 = q3_.x,  W13 = q3_.y,  W14 = q3_.z,  W15 = q3_.w;
    u32 W16 = q4_.x,  W17 = q4_.y,  W18 = q4_.z,  W19 = q4_.w;
    u32 W20 = q5_.x,  W21 = q5_.y,  W22 = q5_.z,  W23 = q5_.w;
    u32 W24 = q6_.x,  W25 = q6_.y,  W26 = q6_.z,  W27 = q6_.w;
    u32 W28 = q7_.x,  W29 = q7_.y,  W30 = q7_.z,  W31 = q7_.w;
    u32 W32 = q8_.x,  W33 = q8_.y,  W34 = q8_.z,  W35 = q8_.w;
    u32 W36 = q9_.x,  W37 = q9_.y,  W38 = q9_.z,  W39 = q9_.w;
    u32 W40 = q10_.x, W41 = q10_.y, W42 = q10_.z, W43 = q10_.w;
    u32 W44 = q11_.x, W45 = q11_.y, W46 = q11_.z, W47 = q11_.w;
    u32 W48 = q12_.x, W49 = q12_.y, W50 = q12_.z, W51 = q12_.w;
    u32 W52 = q13_.x, W53 = q13_.y, W54 = q13_.z, W55 = q13_.w;
    u32 W56 = q14_.x, W57 = q14_.y, W58 = q14_.z, W59 = q14_.w;
    u32 W60 = q15_.x, W61 = q15_.y, W62 = q15_.z, W63 = q15_.w;
    // Opaque pin: single-VGPR "+v" ties (legal, unlike uint4 ties). asm
    // volatile outputs cannot be rematerialized from memory -> the 64
    // weight words must stay register-resident across the loop.
    asm volatile("" : "+v"(W00), "+v"(W01), "+v"(W02), "+v"(W03),
                      "+v"(W04), "+v"(W05), "+v"(W06), "+v"(W07),
                      "+v"(W08), "+v"(W09), "+v"(W10), "+v"(W11),
                      "+v"(W12), "+v"(W13), "+v"(W14), "+v"(W15));
    asm volatile("" : "+v"(W16), "+v"(W17), "+v"(W18), "+v"(W19),
                      "+v"(W20), "+v"(W21), "+v"(W22), "+v"(W23),
                      "+v"(W24), "+v"(W25), "+v"(W26), "+v"(W27),
                      "+v"(W28), "+v"(W29), "+v"(W30), "+v"(W31));
    asm volatile("" : "+v"(W32), "+v"(W33), "+v"(W34), "+v"(W35),
                      "+v"(W36), "+v"(W37), "+v"(W38), "+v"(W39),
                      "+v"(W40), "+v"(W41), "+v"(W42), "+v"(W43),
                      "+v"(W44), "+v"(W45), "+v"(W46), "+v"(W47));
    asm volatile("" : "+v"(W48), "+v"(W49), "+v"(W50), "+v"(W51),
                      "+v"(W52), "+v"(W53), "+v"(W54), "+v"(W55),
                      "+v"(W56), "+v"(W57), "+v"(W58), "+v"(W59),
                      "+v"(W60), "+v"(W61), "+v"(W62), "+v"(W63));

    if (t < 256) ((u32*)hbuf)[t] = 0u;
    __syncthreads();

    f16* xb = xh + (size_t)b * (HWN * RH) + s * 128;  // + step*RH + t
    float xnext = 0.f;
    if (t < 128) xnext = (float)xb[t];

    u64* cb = comm + (size_t)b * 256;  // [parity]*8192 + b*256 + slice*64 + word
    const uint4* hq = (const uint4*)hbuf;

    for (int step = 0; step < HWN; step++) {
        float xcur = xnext;
        if (t < 128 && step + 1 < HWN)
            xnext = (float)xb[(size_t)(step + 1) * RH + t];

        // ---- partial y for 4 rows over this thread's 16 h-pairs
        uint4 q0 = hq[sl*4+0], q1 = hq[sl*4+1], q2 = hq[sl*4+2], q3 = hq[sl*4+3];
        f16x2 H0  = __builtin_bit_cast(f16x2, q0.x), H1  = __builtin_bit_cast(f16x2, q0.y);
        f16x2 H2  = __builtin_bit_cast(f16x2, q0.z), H3  = __builtin_bit_cast(f16x2, q0.w);
        f16x2 H4  = __builtin_bit_cast(f16x2, q1.x), H5  = __builtin_bit_cast(f16x2, q1.y);
        f16x2 H6  = __builtin_bit_cast(f16x2, q1.z), H7  = __builtin_bit_cast(f16x2, q1.w);
        f16x2 H8  = __builtin_bit_cast(f16x2, q2.x), H9  = __builtin_bit_cast(f16x2, q2.y);
        f16x2 H10 = __builtin_bit_cast(f16x2, q2.z), H11 = __builtin_bit_cast(f16x2, q2.w);
        f16x2 H12 = __builtin_bit_cast(f16x2, q3.x), H13 = __builtin_bit_cast(f16x2, q3.y);
        f16x2 H14 = __builtin_bit_cast(f16x2, q3.z), H15 = __builtin_bit_cast(f16x2, q3.w);
        float a0 = 0.f, a1 = 0.f, a2 = 0.f, a3 = 0.f;
        ROW16(a0, W00,W01,W02,W03,W04,W05,W06,W07,W08,W09,W10,W11,W12,W13,W14,W15);
        ROW16(a1, W16,W17,W18,W19,W20,W21,W22,W23,W24,W25,W26,W27,W28,W29,W30,W31);
        ROW16(a2, W32,W33,W34,W35,W36,W37,W38,W39,W40,W41,W42,W43,W44,W45,W46,W47);
        ROW16(a3, W48,W49,W50,W51,W52,W53,W54,W55,W56,W57,W58,W59,W60,W61,W62,W63);
        *(f32x4*)&part[sl][4 * jg] = (f32x4){a0, a1, a2, a3};
        __syncthreads();

        const u32 tag = (u32)(step + 1);
        const size_t pbase = (size_t)(tag & 1) * 8192;

        // ---- waves 4-6: poll for the 3 partner slices (start immediately)
        if (t >= 256 && t < 448) {
            int pi = (t - 256) >> 6;
            int widx = t & 63;
            int p = pi + (pi >= s ? 1 : 0);
            u64* addr = &cb[pbase + p * 64 + widx];
            u64 v  = __hip_atomic_load(addr, __ATOMIC_RELAXED, __HIP_MEMORY_SCOPE_AGENT);
            u64 v2 = __hip_atomic_load(addr, __ATOMIC_RELAXED, __HIP_MEMORY_SCOPE_AGENT);
            int guard = 0;
            while ((u32)(v >> 32) != tag && ++guard < (1 << 17)) {
                v = v2;
                v2 = __hip_atomic_load(addr, __ATOMIC_RELAXED, __HIP_MEMORY_SCOPE_AGENT);
            }
            ((u32*)hbuf)[p * 64 + widx] = (u32)v;
        }
        // ---- waves 0-1: finalize own 128 rows, publish ASAP
        if (t < 128) {
            float y = xcur;
            #pragma unroll
            for (int k = 0; k < 16; k++) y += part[k][t];
            float h = tanhf(y);
            f16 hf = (f16)h;
            u32 hu = (u32)__builtin_bit_cast(unsigned short, hf);
            u32 other = (u32)__shfl_down((int)hu, 1, 64);
            if ((t & 1) == 0) {
                u64 v = ((u64)tag << 32) | (u64)(hu | (other << 16));
                __hip_atomic_store(&cb[pbase + s * 64 + (t >> 1)], v,
                                   __ATOMIC_RELAXED, __HIP_MEMORY_SCOPE_AGENT);
            }
            hbuf[s * 128 + t] = hf;                 // own slice into local h
            xb[(size_t)step * RH + t] = hf;         // hs output (in place)
        }
        __syncthreads();
    }
}

// ------------------------------------------------------------------ launch
extern "C" void kernel_launch(void* const* d_in, const int* in_sizes, int n_in,
                              void* d_out, int out_size, void* d_ws, size_t ws_size,
                              hipStream_t stream) {
    const float* x     = (const float*)d_in[0];
    const float* gamma = (const float*)d_in[1];
    const float* beta  = (const float*)d_in[2];
    const float* w_in  = (const float*)d_in[3];
    const float* b_in  = (const float*)d_in[4];
    const float* w_ih  = (const float*)d_in[5];
    const float* b_ih  = (const float*)d_in[6];
    const float* w_hh  = (const float*)d_in[7];
    const float* b_hh  = (const float*)d_in[8];
    const float* w_out = (const float*)d_in[9];
    const float* b_out = (const float*)d_in[10];

    char* ws = (char*)d_ws;
    float* scale   = (float*)(ws + 0);         //   512 B
    float* shift   = (float*)(ws + 512);       //   512 B
    float* bihh    = (float*)(ws + 1024);      //  2 KB
    f16*   w_in_h  = (f16*)(ws + 4096);        // 64 KB
    f16*   w_ih_h  = (f16*)(ws + 69632);       // 256 KB
    f16*   w_out_h = (f16*)(ws + 331776);      // 128 KB
    u32*   wr      = (u32*)(ws + 462848);      // 512 KB packed W_hh
    u64*   comm    = (u64*)(ws + 987136);      // 128 KB h-exchange
    f16*   xh      = (f16*)(ws + 1179648);     // 32 MB xgate, overwritten by hs
    f16*   A1      = (f16*)(ws + 34734080);    //  8 MB
    f16*   inp     = (f16*)(ws + 43122688);    // 16 MB (ends 59899904)

    bn_stats_kernel<<<128, 256, 0, stream>>>(x, gamma, beta, scale, shift);
    prep_w_kernel<<<1474, 256, 0, stream>>>(w_in, w_ih, w_out, w_hh, b_ih, b_hh,
                                            w_in_h, w_ih_h, w_out_h, wr, bihh, comm);
    prep_x_kernel<<<dim3(32, 4, 32), dim3(32, 8), 0, stream>>>(x, scale, shift, A1);
    gemm_kernel<0><<<dim3(128, 4), 256, 0, stream>>>(A1, w_in_h, b_in, (void*)inp, RIN, CC);
    gemm_kernel<1><<<dim3(128, 8), 256, 0, stream>>>(inp, w_ih_h, bihh, (void*)xh, RH, RIN);
    rnn_kernel<<<128, 512, 0, stream>>>(wr, xh, comm);
    gemm_kernel<2><<<dim3(128, 2), 256, 0, stream>>>(xh, w_out_h, b_out, d_out, OCN, RH);
}

// Round 3
// 1698.370 us; speedup vs baseline: 1.0243x; 1.0243x over previous
//
#include <hip/hip_runtime.h>
#include <hip/hip_fp16.h>

typedef _Float16 f16;
typedef _Float16 f16x2 __attribute__((ext_vector_type(2)));
typedef _Float16 f16x8 __attribute__((ext_vector_type(8)));
typedef float    f32x4 __attribute__((ext_vector_type(4)));
typedef unsigned int u32;
typedef unsigned long long u64;

#define BN_EPS 1e-5f

static constexpr int BB  = 32;    // batch
static constexpr int CC  = 128;   // channels
static constexpr int HWN = 1024;  // H*W = L
static constexpr int RIN = 256;
static constexpr int RH  = 512;
static constexpr int OCN = 128;

// ---------------------------------------------------------------- BN stats
__global__ void bn_stats_kernel(const float* __restrict__ x,
                                const float* __restrict__ gamma,
                                const float* __restrict__ beta,
                                float* __restrict__ scale,
                                float* __restrict__ shift) {
    int c = blockIdx.x;
    int tid = threadIdx.x;
    float s = 0.f, s2 = 0.f;
    const float* xc = x + (size_t)c * HWN;
    for (int idx = tid; idx < BB * HWN; idx += 256) {
        int b = idx >> 10, hw = idx & 1023;
        float v = xc[(size_t)b * (CC * HWN) + hw];
        s += v; s2 += v * v;
    }
    for (int off = 32; off > 0; off >>= 1) {
        s  += __shfl_down(s, off, 64);
        s2 += __shfl_down(s2, off, 64);
    }
    __shared__ float ls[4], ls2[4];
    int wv = tid >> 6, ln = tid & 63;
    if (ln == 0) { ls[wv] = s; ls2[wv] = s2; }
    __syncthreads();
    if (tid == 0) {
        float ts  = ls[0] + ls[1] + ls[2] + ls[3];
        float ts2 = ls2[0] + ls2[1] + ls2[2] + ls2[3];
        const float inv_n = 1.0f / (BB * HWN);
        float mean = ts * inv_n;
        float var  = ts2 * inv_n - mean * mean;
        float rstd = rsqrtf(var + BN_EPS);
        float sc = gamma[c] * rstd;
        scale[c] = sc;
        shift[c] = beta[c] - mean * sc;
    }
}

// ------------------------------------------- normalize + transpose -> A1 f16
__global__ void prep_x_kernel(const float* __restrict__ x,
                              const float* __restrict__ scale,
                              const float* __restrict__ shift,
                              f16* __restrict__ A1) {
    __shared__ float tile[32][33];
    int tx = threadIdx.x, ty = threadIdx.y;  // 32 x 8
    int hb = blockIdx.x, cb = blockIdx.y, b = blockIdx.z;
    #pragma unroll
    for (int k = 0; k < 4; k++) {
        int c  = cb * 32 + ty + 8 * k;
        int hw = hb * 32 + tx;
        tile[ty + 8 * k][tx] = x[(size_t)b * (CC * HWN) + (size_t)c * HWN + hw];
    }
    __syncthreads();
    #pragma unroll
    for (int k = 0; k < 4; k++) {
        int hw = hb * 32 + ty + 8 * k;
        int c  = cb * 32 + tx;
        float v = tile[tx][ty + 8 * k];
        A1[(size_t)(b * HWN + hw) * CC + c] = (f16)(v * scale[c] + shift[c]);
    }
}

// ------------------------------------------------------------ weight prep
__global__ void prep_w_kernel(const float* __restrict__ w_in,
                              const float* __restrict__ w_ih,
                              const float* __restrict__ w_out,
                              const float* __restrict__ w_hh,
                              const float* __restrict__ b_ih,
                              const float* __restrict__ b_hh,
                              f16* __restrict__ w_in_h,
                              f16* __restrict__ w_ih_h,
                              f16* __restrict__ w_out_h,
                              u32* __restrict__ wr,
                              float* __restrict__ bihh,
                              u64* __restrict__ comm) {
    int idx = blockIdx.x * 256 + threadIdx.x;
    if (idx < 32768) { w_in_h[idx] = (f16)w_in[idx]; return; }
    idx -= 32768;
    if (idx < 131072) { w_ih_h[idx] = (f16)w_ih[idx]; return; }
    idx -= 131072;
    if (idx < 65536) { w_out_h[idx] = (f16)w_out[idx]; return; }
    idx -= 65536;
    if (idx < 131072) {
        // word idx -> (slice s, thread t, reg k); reg k = r*16+n
        int s = idx >> 15, rem = idx & 32767;
        int t = rem >> 6, k = rem & 63;
        int r = k >> 4, n = k & 15;
        int jg = t & 31, sl = t >> 5;
        int j  = s * 128 + 4 * jg + r;       // output row
        int i2 = sl * 16 + n;                // h-pair index
        f16 lo = (f16)w_hh[(size_t)j * 512 + 2 * i2];
        f16 hi = (f16)w_hh[(size_t)j * 512 + 2 * i2 + 1];
        wr[idx] = (u32)__builtin_bit_cast(unsigned short, lo) |
                  ((u32)__builtin_bit_cast(unsigned short, hi) << 16);
        return;
    }
    idx -= 131072;
    if (idx < 512) { bihh[idx] = b_ih[idx] + b_hh[idx]; return; }
    idx -= 512;
    if (idx < 16384) comm[idx] = 0ULL;
}

// ------------------------------------------------------------- MFMA GEMM
template <int MODE>
__global__ void gemm_kernel(const f16* __restrict__ A,
                            const f16* __restrict__ W,
                            const float* __restrict__ bias,
                            void* __restrict__ outp,
                            int N, int K) {
    int wave = threadIdx.x >> 6;
    int lane = threadIdx.x & 63;
    int q = lane >> 4, r = lane & 15;
    int bm = blockIdx.x * 256 + wave * 64;
    int bn = blockIdx.y * 64;

    f32x4 acc[4][4];
    #pragma unroll
    for (int i = 0; i < 4; i++)
        #pragma unroll
        for (int j = 0; j < 4; j++)
            acc[i][j] = (f32x4){0.f, 0.f, 0.f, 0.f};

    const f16* Ap = A + (size_t)(bm + r) * K + 8 * q;
    const f16* Wp = W + (size_t)(bn + r) * K + 8 * q;

    for (int k = 0; k < K; k += 32) {
        f16x8 av[4], bv[4];
        #pragma unroll
        for (int i = 0; i < 4; i++)
            av[i] = *(const f16x8*)(Ap + (size_t)(16 * i) * K + k);
        #pragma unroll
        for (int i = 0; i < 4; i++)
            bv[i] = *(const f16x8*)(Wp + (size_t)(16 * i) * K + k);
        #pragma unroll
        for (int mi = 0; mi < 4; mi++)
            #pragma unroll
            for (int ni = 0; ni < 4; ni++)
                acc[mi][ni] = __builtin_amdgcn_mfma_f32_16x16x32_f16(
                    av[mi], bv[ni], acc[mi][ni], 0, 0, 0);
    }

    #pragma unroll
    for (int mi = 0; mi < 4; mi++) {
        #pragma unroll
        for (int ni = 0; ni < 4; ni++) {
            int col = bn + 16 * ni + r;
            float bval = bias[col];
            #pragma unroll
            for (int i = 0; i < 4; i++) {
                int row = bm + 16 * mi + 4 * q + i;
                float val = acc[mi][ni][i] + bval;
                if (MODE == 0) {
                    val = val - tanhf(val);
                    ((f16*)outp)[(size_t)row * N + col] = (f16)val;
                } else if (MODE == 1) {
                    ((f16*)outp)[(size_t)row * N + col] = (f16)val;
                } else {
                    int b = row >> 10, hw = row & 1023;
                    ((float*)outp)[(size_t)b * (OCN * HWN) + (size_t)col * HWN + hw] = val;
                }
            }
        }
    }
}

// ---------------------------------------------------------------- RNN scan
// 4 slices x 32 batches = 128 WGs (1 per CU). W_hh slice kept in registers.
// Mechanism history (rounds 3-9): local array -> SROA fails -> scratch;
// named SSA from __restrict__ ptr -> invariant-load REMAT from L2 every
// step (VGPR 52, 3320 cyc/step); "+v" on uint4 -> compile error; 64x u32
// asm-volatile pin -> values SPILLED to scratch (VGPR still 52, slower).
// ROOT CAUSE of both remat and spill: launch_bounds' 2nd arg is only a
// MINIMUM waves/EU; the allocator opportunistically targets 8 waves/EU
// (52 VGPR) even though only 2 waves/EU ever run (128 8-wave WGs on 256
// CUs). THIS round: amdgpu_waves_per_eu(2,2) pins the occupancy target ==
// actual occupancy -> budget 256 VGPR -> the ~140-reg live set fits, no
// remat, no spill. asm pin kept as remat backstop. Verify: VGPR_Count>=128.
// Cross-WG h exchange: RELAXED u64 atomics (payload+tag in one word,
// parity double-buffer); pollers on waves 4-6, finalize on waves 0-1.
__device__ __forceinline__ float dot2acc(u32 w, f16x2 h, float c) {
#if __has_builtin(__builtin_amdgcn_fdot2)
    return __builtin_amdgcn_fdot2(__builtin_bit_cast(f16x2, w), h, c, false);
#else
    f16x2 a = __builtin_bit_cast(f16x2, w);
    return c + (float)a[0] * (float)h[0] + (float)a[1] * (float)h[1];
#endif
}

#define ROW16(acc, a,b,c,d,e,f,g,h,i,j,k,l,m,n,o,p)                \
    acc = dot2acc(a, H0,  acc); acc = dot2acc(b, H1,  acc);        \
    acc = dot2acc(c, H2,  acc); acc = dot2acc(d, H3,  acc);        \
    acc = dot2acc(e, H4,  acc); acc = dot2acc(f, H5,  acc);        \
    acc = dot2acc(g, H6,  acc); acc = dot2acc(h, H7,  acc);        \
    acc = dot2acc(i, H8,  acc); acc = dot2acc(j, H9,  acc);        \
    acc = dot2acc(k, H10, acc); acc = dot2acc(l, H11, acc);        \
    acc = dot2acc(m, H12, acc); acc = dot2acc(n, H13, acc);        \
    acc = dot2acc(o, H14, acc); acc = dot2acc(p, H15, acc)

__global__ void __launch_bounds__(512)
__attribute__((amdgpu_waves_per_eu(2, 2)))
rnn_kernel(const u32* WR, f16* __restrict__ xh, u64* comm) {
    const int wg = blockIdx.x;
    const int b  = wg & 31;   // batch  (4 slices of a batch share wg%8 -> same XCD)
    const int s  = wg >> 5;   // slice: rows [128s, 128s+128)
    const int t  = threadIdx.x;
    const int jg = t & 31;    // 4 rows: 128s + 4jg .. +3
    const int sl = t >> 5;    // 16 h-pair slices of 16 pairs

    __shared__ __align__(16) f16 hbuf[512];
    __shared__ float part[16][128];

    // this thread's 64 weight words: 16x dwordx4 -> 64 named u32 scalars.
    const uint4* wp = (const uint4*)(WR + ((size_t)(s * 512 + t) << 6));
    uint4 q0_  = wp[0],  q1_  = wp[1],  q2_  = wp[2],  q3_  = wp[3];
    uint4 q4_  = wp[4],  q5_  = wp[5],  q6_  = wp[6],  q7_  = wp[7];
    uint4 q8_  = wp[8],  q9_  = wp[9],  q10_ = wp[10], q11_ = wp[11];
    uint4 q12_ = wp[12], q13_ = wp[13], q14_ = wp[14], q15_ = wp[15];
    u32 W00 = q0_.x,  W01 = q0_.y,  W02 = q0_.z,  W03 = q0_.w;
    u32 W04 = q1_.x,  W05 = q1_.y,  W06 = q1_.z,  W07 = q1_.w;
    u32 W08 = q2_.x,  W09 = q2_.y,  W10 = q2_.z,  W11 = q2_.w;
    u32 W12 = q3_.x,  W13 = q3_.y,  W14 = q3_.z,  W15 = q3_.w;
    u32 W16 = q4_.x,  W17 = q4_.y,  W18 = q4_.z,  W19 = q4_.w;
    u32 W20 = q5_.x,  W21 = q5_.y,  W22 = q5_.z,  W23 = q5_.w;
    u32 W24 = q6_.x,  W25 = q6_.y,  W26 = q6_.z,  W27 = q6_.w;
    u32 W28 = q7_.x,  W29 = q7_.y,  W30 = q7_.z,  W31 = q7_.w;
    u32 W32 = q8_.x,  W33 = q8_.y,  W34 = q8_.z,  W35 = q8_.w;
    u32 W36 = q9_.x,  W37 = q9_.y,  W38 = q9_.z,  W39 = q9_.w;
    u32 W40 = q10_.x, W41 = q10_.y, W42 = q10_.z, W43 = q10_.w;
    u32 W44 = q11_.x, W45 = q11_.y, W46 = q11_.z, W47 = q11_.w;
    u32 W48 = q12_.x, W49 = q12_.y, W50 = q12_.z, W51 = q12_.w;
    u32 W52 = q13_.x, W53 = q13_.y, W54 = q13_.z, W55 = q13_.w;
    u32 W56 = q14_.x, W57 = q14_.y, W58 = q14_.z, W59 = q14_.w;
    u32 W60 = q15_.x, W61 = q15_.y, W62 = q15_.z, W63 = q15_.w;
    // Opaque pin (remat backstop): asm volatile outputs cannot be
    // rematerialized from memory. With waves_per_eu(2,2) there is no
    // occupancy pressure either -> values stay register-resident.
    asm volatile("" : "+v"(W00), "+v"(W01), "+v"(W02), "+v"(W03),
                      "+v"(W04), "+v"(W05), "+v"(W06), "+v"(W07),
                      "+v"(W08), "+v"(W09), "+v"(W10), "+v"(W11),
                      "+v"(W12), "+v"(W13), "+v"(W14), "+v"(W15));
    asm volatile("" : "+v"(W16), "+v"(W17), "+v"(W18), "+v"(W19),
                      "+v"(W20), "+v"(W21), "+v"(W22), "+v"(W23),
                      "+v"(W24), "+v"(W25), "+v"(W26), "+v"(W27),
                      "+v"(W28), "+v"(W29), "+v"(W30), "+v"(W31));
    asm volatile("" : "+v"(W32), "+v"(W33), "+v"(W34), "+v"(W35),
                      "+v"(W36), "+v"(W37), "+v"(W38), "+v"(W39),
                      "+v"(W40), "+v"(W41), "+v"(W42), "+v"(W43),
                      "+v"(W44), "+v"(W45), "+v"(W46), "+v"(W47));
    asm volatile("" : "+v"(W48), "+v"(W49), "+v"(W50), "+v"(W51),
                      "+v"(W52), "+v"(W53), "+v"(W54), "+v"(W55),
                      "+v"(W56), "+v"(W57), "+v"(W58), "+v"(W59),
                      "+v"(W60), "+v"(W61), "+v"(W62), "+v"(W63));

    if (t < 256) ((u32*)hbuf)[t] = 0u;
    __syncthreads();

    f16* xb = xh + (size_t)b * (HWN * RH) + s * 128;  // + step*RH + t
    float xnext = 0.f;
    if (t < 128) xnext = (float)xb[t];

    u64* cb = comm + (size_t)b * 256;  // [parity]*8192 + b*256 + slice*64 + word
    const uint4* hq = (const uint4*)hbuf;

    for (int step = 0; step < HWN; step++) {
        float xcur = xnext;
        if (t < 128 && step + 1 < HWN)
            xnext = (float)xb[(size_t)(step + 1) * RH + t];

        // ---- partial y for 4 rows over this thread's 16 h-pairs
        uint4 q0 = hq[sl*4+0], q1 = hq[sl*4+1], q2 = hq[sl*4+2], q3 = hq[sl*4+3];
        f16x2 H0  = __builtin_bit_cast(f16x2, q0.x), H1  = __builtin_bit_cast(f16x2, q0.y);
        f16x2 H2  = __builtin_bit_cast(f16x2, q0.z), H3  = __builtin_bit_cast(f16x2, q0.w);
        f16x2 H4  = __builtin_bit_cast(f16x2, q1.x), H5  = __builtin_bit_cast(f16x2, q1.y);
        f16x2 H6  = __builtin_bit_cast(f16x2, q1.z), H7  = __builtin_bit_cast(f16x2, q1.w);
        f16x2 H8  = __builtin_bit_cast(f16x2, q2.x), H9  = __builtin_bit_cast(f16x2, q2.y);
        f16x2 H10 = __builtin_bit_cast(f16x2, q2.z), H11 = __builtin_bit_cast(f16x2, q2.w);
        f16x2 H12 = __builtin_bit_cast(f16x2, q3.x), H13 = __builtin_bit_cast(f16x2, q3.y);
        f16x2 H14 = __builtin_bit_cast(f16x2, q3.z), H15 = __builtin_bit_cast(f16x2, q3.w);
        float a0 = 0.f, a1 = 0.f, a2 = 0.f, a3 = 0.f;
        ROW16(a0, W00,W01,W02,W03,W04,W05,W06,W07,W08,W09,W10,W11,W12,W13,W14,W15);
        ROW16(a1, W16,W17,W18,W19,W20,W21,W22,W23,W24,W25,W26,W27,W28,W29,W30,W31);
        ROW16(a2, W32,W33,W34,W35,W36,W37,W38,W39,W40,W41,W42,W43,W44,W45,W46,W47);
        ROW16(a3, W48,W49,W50,W51,W52,W53,W54,W55,W56,W57,W58,W59,W60,W61,W62,W63);
        *(f32x4*)&part[sl][4 * jg] = (f32x4){a0, a1, a2, a3};
        __syncthreads();

        const u32 tag = (u32)(step + 1);
        const size_t pbase = (size_t)(tag & 1) * 8192;

        // ---- waves 4-6: poll for the 3 partner slices (start immediately)
        if (t >= 256 && t < 448) {
            int pi = (t - 256) >> 6;
            int widx = t & 63;
            int p = pi + (pi >= s ? 1 : 0);
            u64* addr = &cb[pbase + p * 64 + widx];
            u64 v  = __hip_atomic_load(addr, __ATOMIC_RELAXED, __HIP_MEMORY_SCOPE_AGENT);
            u64 v2 = __hip_atomic_load(addr, __ATOMIC_RELAXED, __HIP_MEMORY_SCOPE_AGENT);
            int guard = 0;
            while ((u32)(v >> 32) != tag && ++guard < (1 << 17)) {
                v = v2;
                v2 = __hip_atomic_load(addr, __ATOMIC_RELAXED, __HIP_MEMORY_SCOPE_AGENT);
            }
            ((u32*)hbuf)[p * 64 + widx] = (u32)v;
        }
        // ---- waves 0-1: finalize own 128 rows, publish ASAP
        if (t < 128) {
            float y = xcur;
            #pragma unroll
            for (int k = 0; k < 16; k++) y += part[k][t];
            float h = tanhf(y);
            f16 hf = (f16)h;
            u32 hu = (u32)__builtin_bit_cast(unsigned short, hf);
            u32 other = (u32)__shfl_down((int)hu, 1, 64);
            if ((t & 1) == 0) {
                u64 v = ((u64)tag << 32) | (u64)(hu | (other << 16));
                __hip_atomic_store(&cb[pbase + s * 64 + (t >> 1)], v,
                                   __ATOMIC_RELAXED, __HIP_MEMORY_SCOPE_AGENT);
            }
            hbuf[s * 128 + t] = hf;                 // own slice into local h
            xb[(size_t)step * RH + t] = hf;         // hs output (in place)
        }
        __syncthreads();
    }
}

// ------------------------------------------------------------------ launch
extern "C" void kernel_launch(void* const* d_in, const int* in_sizes, int n_in,
                              void* d_out, int out_size, void* d_ws, size_t ws_size,
                              hipStream_t stream) {
    const float* x     = (const float*)d_in[0];
    const float* gamma = (const float*)d_in[1];
    const float* beta  = (const float*)d_in[2];
    const float* w_in  = (const float*)d_in[3];
    const float* b_in  = (const float*)d_in[4];
    const float* w_ih  = (const float*)d_in[5];
    const float* b_ih  = (const float*)d_in[6];
    const float* w_hh  = (const float*)d_in[7];
    const float* b_hh  = (const float*)d_in[8];
    const float* w_out = (const float*)d_in[9];
    const float* b_out = (const float*)d_in[10];

    char* ws = (char*)d_ws;
    float* scale   = (float*)(ws + 0);         //   512 B
    float* shift   = (float*)(ws + 512);       //   512 B
    float* bihh    = (float*)(ws + 1024);      //  2 KB
    f16*   w_in_h  = (f16*)(ws + 4096);        // 64 KB
    f16*   w_ih_h  = (f16*)(ws + 69632);       // 256 KB
    f16*   w_out_h = (f16*)(ws + 331776);      // 128 KB
    u32*   wr      = (u32*)(ws + 462848);      // 512 KB packed W_hh
    u64*   comm    = (u64*)(ws + 987136);      // 128 KB h-exchange
    f16*   xh      = (f16*)(ws + 1179648);     // 32 MB xgate, overwritten by hs
    f16*   A1      = (f16*)(ws + 34734080);    //  8 MB
    f16*   inp     = (f16*)(ws + 43122688);    // 16 MB (ends 59899904)

    bn_stats_kernel<<<128, 256, 0, stream>>>(x, gamma, beta, scale, shift);
    prep_w_kernel<<<1474, 256, 0, stream>>>(w_in, w_ih, w_out, w_hh, b_ih, b_hh,
                                            w_in_h, w_ih_h, w_out_h, wr, bihh, comm);
    prep_x_kernel<<<dim3(32, 4, 32), dim3(32, 8), 0, stream>>>(x, scale, shift, A1);
    gemm_kernel<0><<<dim3(128, 4), 256, 0, stream>>>(A1, w_in_h, b_in, (void*)inp, RIN, CC);
    gemm_kernel<1><<<dim3(128, 8), 256, 0, stream>>>(inp, w_ih_h, bihh, (void*)xh, RH, RIN);
    rnn_kernel<<<128, 512, 0, stream>>>(wr, xh, comm);
    gemm_kernel<2><<<dim3(128, 2), 256, 0, stream>>>(xh, w_out_h, b_out, d_out, OCN, RH);
}

// Round 4
// 1652.808 us; speedup vs baseline: 1.0526x; 1.0276x over previous
//
#include <hip/hip_runtime.h>
#include <hip/hip_fp16.h>

typedef _Float16 f16;
typedef _Float16 f16x2 __attribute__((ext_vector_type(2)));
typedef _Float16 f16x8 __attribute__((ext_vector_type(8)));
typedef float    f32x4 __attribute__((ext_vector_type(4)));
typedef unsigned int u32;
typedef unsigned long long u64;

#define BN_EPS 1e-5f

static constexpr int BB  = 32;    // batch
static constexpr int CC  = 128;   // channels
static constexpr int HWN = 1024;  // H*W = L
static constexpr int RIN = 256;
static constexpr int RH  = 512;
static constexpr int OCN = 128;

// ---------------------------------------------------------------- BN stats
__global__ void bn_stats_kernel(const float* __restrict__ x,
                                const float* __restrict__ gamma,
                                const float* __restrict__ beta,
                                float* __restrict__ scale,
                                float* __restrict__ shift) {
    int c = blockIdx.x;
    int tid = threadIdx.x;
    float s = 0.f, s2 = 0.f;
    const float* xc = x + (size_t)c * HWN;
    for (int idx = tid; idx < BB * HWN; idx += 256) {
        int b = idx >> 10, hw = idx & 1023;
        float v = xc[(size_t)b * (CC * HWN) + hw];
        s += v; s2 += v * v;
    }
    for (int off = 32; off > 0; off >>= 1) {
        s  += __shfl_down(s, off, 64);
        s2 += __shfl_down(s2, off, 64);
    }
    __shared__ float ls[4], ls2[4];
    int wv = tid >> 6, ln = tid & 63;
    if (ln == 0) { ls[wv] = s; ls2[wv] = s2; }
    __syncthreads();
    if (tid == 0) {
        float ts  = ls[0] + ls[1] + ls[2] + ls[3];
        float ts2 = ls2[0] + ls2[1] + ls2[2] + ls2[3];
        const float inv_n = 1.0f / (BB * HWN);
        float mean = ts * inv_n;
        float var  = ts2 * inv_n - mean * mean;
        float rstd = rsqrtf(var + BN_EPS);
        float sc = gamma[c] * rstd;
        scale[c] = sc;
        shift[c] = beta[c] - mean * sc;
    }
}

// ------------------------------------------- normalize + transpose -> A1 f16
__global__ void prep_x_kernel(const float* __restrict__ x,
                              const float* __restrict__ scale,
                              const float* __restrict__ shift,
                              f16* __restrict__ A1) {
    __shared__ float tile[32][33];
    int tx = threadIdx.x, ty = threadIdx.y;  // 32 x 8
    int hb = blockIdx.x, cb = blockIdx.y, b = blockIdx.z;
    #pragma unroll
    for (int k = 0; k < 4; k++) {
        int c  = cb * 32 + ty + 8 * k;
        int hw = hb * 32 + tx;
        tile[ty + 8 * k][tx] = x[(size_t)b * (CC * HWN) + (size_t)c * HWN + hw];
    }
    __syncthreads();
    #pragma unroll
    for (int k = 0; k < 4; k++) {
        int hw = hb * 32 + ty + 8 * k;
        int c  = cb * 32 + tx;
        float v = tile[tx][ty + 8 * k];
        A1[(size_t)(b * HWN + hw) * CC + c] = (f16)(v * scale[c] + shift[c]);
    }
}

// ------------------------------------------------------------ weight prep
// wr layout for the 8-slice rnn: word idx = (s*512 + t)*32 + w.
// Thread t: row r=t>>3 (global j=s*64+r), chunk c=t&7 (h-pairs [32c,32c+32)).
// Word w = 4i+k maps to h-pair i2 = 32c + 4*(i XOR c) + k  -- the XOR folds
// the LDS bank-conflict-free read swizzle into the weight ordering.
__global__ void prep_w_kernel(const float* __restrict__ w_in,
                              const float* __restrict__ w_ih,
                              const float* __restrict__ w_out,
                              const float* __restrict__ w_hh,
                              const float* __restrict__ b_ih,
                              const float* __restrict__ b_hh,
                              f16* __restrict__ w_in_h,
                              f16* __restrict__ w_ih_h,
                              f16* __restrict__ w_out_h,
                              u32* __restrict__ wr,
                              float* __restrict__ bihh,
                              u32* __restrict__ comm) {
    int idx = blockIdx.x * 256 + threadIdx.x;
    if (idx < 32768) { w_in_h[idx] = (f16)w_in[idx]; return; }
    idx -= 32768;
    if (idx < 131072) { w_ih_h[idx] = (f16)w_ih[idx]; return; }
    idx -= 131072;
    if (idx < 65536) { w_out_h[idx] = (f16)w_out[idx]; return; }
    idx -= 65536;
    if (idx < 131072) {
        int s = idx >> 14, rem = idx & 16383;
        int t = rem >> 5, w = rem & 31;
        int r = t >> 3, c = t & 7;
        int i = w >> 2, k = w & 3;
        int i2 = c * 32 + 4 * (i ^ c) + k;   // h-pair index
        int j  = s * 64 + r;                 // output row
        f16 lo = (f16)w_hh[(size_t)j * 512 + 2 * i2];
        f16 hi = (f16)w_hh[(size_t)j * 512 + 2 * i2 + 1];
        wr[idx] = (u32)__builtin_bit_cast(unsigned short, lo) |
                  ((u32)__builtin_bit_cast(unsigned short, hi) << 16);
        return;
    }
    idx -= 131072;
    if (idx < 512) { bihh[idx] = b_ih[idx] + b_hh[idx]; return; }
    idx -= 512;
    if (idx < 32768) comm[idx] = 0u;   // 2 parities x 32 b x 512 rows
}

// ------------------------------------------------------------- MFMA GEMM
template <int MODE>
__global__ void gemm_kernel(const f16* __restrict__ A,
                            const f16* __restrict__ W,
                            const float* __restrict__ bias,
                            void* __restrict__ outp,
                            int N, int K) {
    int wave = threadIdx.x >> 6;
    int lane = threadIdx.x & 63;
    int q = lane >> 4, r = lane & 15;
    int bm = blockIdx.x * 256 + wave * 64;
    int bn = blockIdx.y * 64;

    f32x4 acc[4][4];
    #pragma unroll
    for (int i = 0; i < 4; i++)
        #pragma unroll
        for (int j = 0; j < 4; j++)
            acc[i][j] = (f32x4){0.f, 0.f, 0.f, 0.f};

    const f16* Ap = A + (size_t)(bm + r) * K + 8 * q;
    const f16* Wp = W + (size_t)(bn + r) * K + 8 * q;

    for (int k = 0; k < K; k += 32) {
        f16x8 av[4], bv[4];
        #pragma unroll
        for (int i = 0; i < 4; i++)
            av[i] = *(const f16x8*)(Ap + (size_t)(16 * i) * K + k);
        #pragma unroll
        for (int i = 0; i < 4; i++)
            bv[i] = *(const f16x8*)(Wp + (size_t)(16 * i) * K + k);
        #pragma unroll
        for (int mi = 0; mi < 4; mi++)
            #pragma unroll
            for (int ni = 0; ni < 4; ni++)
                acc[mi][ni] = __builtin_amdgcn_mfma_f32_16x16x32_f16(
                    av[mi], bv[ni], acc[mi][ni], 0, 0, 0);
    }

    #pragma unroll
    for (int mi = 0; mi < 4; mi++) {
        #pragma unroll
        for (int ni = 0; ni < 4; ni++) {
            int col = bn + 16 * ni + r;
            float bval = bias[col];
            #pragma unroll
            for (int i = 0; i < 4; i++) {
                int row = bm + 16 * mi + 4 * q + i;
                float val = acc[mi][ni][i] + bval;
                if (MODE == 0) {
                    val = val - tanhf(val);
                    ((f16*)outp)[(size_t)row * N + col] = (f16)val;
                } else if (MODE == 1) {
                    ((f16*)outp)[(size_t)row * N + col] = (f16)val;
                } else {
                    int b = row >> 10, hw = row & 1023;
                    ((float*)outp)[(size_t)b * (OCN * HWN) + (size_t)col * HWN + hw] = val;
                }
            }
        }
    }
}

// ---------------------------------------------------------------- RNN scan
// Round-4 redesign. Evidence (R0 remat 1417us / R2 spill 1535 / R3 resident?
// 1500 all within 6%): the weight path is NOT the bottleneck; the per-step
// critical path is exchange RT + LDS-reduce + 2 barriers (~3300 cyc/step,
// VALUBusy 10%, HBM 1.5%).  New structure shortens serial step work:
//  * 8 slices x 32 batches = 256 WGs (1/CU). 64 rows/WG, 32 weight
//    words/thread -> ~80 live regs, register-resident without a fight.
//  * thread map: row r = t>>3 (8 lanes/row), chunk c = t&7. Partial dot
//    reduced by 3x shfl_xor IN-WAVE -> no part[] LDS round trip.
//  * hbuf double-buffered by step parity -> ONE __syncthreads per step.
//  * publish: leaders (c==0) store u32 (tag16|h16) per row, relaxed agent
//    atomics, parity slots (ABA-safe: partner can't be 2 steps ahead).
//  * poll: 448 pollers (t>=64), ONE word each; speculative pre-poll at
//    iter start overlaps matvec and absorbs WG skew.
//  * LDS h reads: XOR-swizzle (i^c) folded into weight packing ->
//    8-way-broadcast conflict-free ds_read_b128.
__device__ __forceinline__ float dot2acc(u32 w, f16x2 h, float c) {
#if __has_builtin(__builtin_amdgcn_fdot2)
    return __builtin_amdgcn_fdot2(__builtin_bit_cast(f16x2, w), h, c, false);
#else
    f16x2 a = __builtin_bit_cast(f16x2, w);
    return c + (float)a[0] * (float)h[0] + (float)a[1] * (float)h[1];
#endif
}

__device__ __forceinline__ f16x2 u2h(u32 w) { return __builtin_bit_cast(f16x2, w); }

__global__ void __launch_bounds__(512)
__attribute__((amdgpu_waves_per_eu(2, 2)))
rnn_kernel(const u32* WR, f16* __restrict__ xh, u32* comm) {
    const int wg = blockIdx.x;
    const int b  = wg & 31;    // batch; slices of batch b at wg = b+32s -> same wg%8 -> same XCD
    const int s  = wg >> 5;    // slice 0..7: rows [64s, 64s+64)
    const int t  = threadIdx.x;
    const int r  = t >> 3;     // local row 0..63
    const int c  = t & 7;      // h-chunk: pairs [32c, 32c+32)
    const bool leader = (c == 0);

    __shared__ __align__(16) f16 hbuf[2][512];

    // ---- 32 resident weight words (8x dwordx4)
    const uint4* wp = (const uint4*)(WR + ((size_t)(s * 512 + t) << 5));
    uint4 q0_ = wp[0], q1_ = wp[1], q2_ = wp[2], q3_ = wp[3];
    uint4 q4_ = wp[4], q5_ = wp[5], q6_ = wp[6], q7_ = wp[7];
    u32 W00 = q0_.x, W01 = q0_.y, W02 = q0_.z, W03 = q0_.w;
    u32 W04 = q1_.x, W05 = q1_.y, W06 = q1_.z, W07 = q1_.w;
    u32 W08 = q2_.x, W09 = q2_.y, W10 = q2_.z, W11 = q2_.w;
    u32 W12 = q3_.x, W13 = q3_.y, W14 = q3_.z, W15 = q3_.w;
    u32 W16 = q4_.x, W17 = q4_.y, W18 = q4_.z, W19 = q4_.w;
    u32 W20 = q5_.x, W21 = q5_.y, W22 = q5_.z, W23 = q5_.w;
    u32 W24 = q6_.x, W25 = q6_.y, W26 = q6_.z, W27 = q6_.w;
    u32 W28 = q7_.x, W29 = q7_.y, W30 = q7_.z, W31 = q7_.w;
    // remat backstop (asm outputs can't be re-loaded from memory)
    asm volatile("" : "+v"(W00), "+v"(W01), "+v"(W02), "+v"(W03),
                      "+v"(W04), "+v"(W05), "+v"(W06), "+v"(W07),
                      "+v"(W08), "+v"(W09), "+v"(W10), "+v"(W11),
                      "+v"(W12), "+v"(W13), "+v"(W14), "+v"(W15));
    asm volatile("" : "+v"(W16), "+v"(W17), "+v"(W18), "+v"(W19),
                      "+v"(W20), "+v"(W21), "+v"(W22), "+v"(W23),
                      "+v"(W24), "+v"(W25), "+v"(W26), "+v"(W27),
                      "+v"(W28), "+v"(W29), "+v"(W30), "+v"(W31));

    ((u32*)hbuf)[t] = 0u;          // zero both parities (2KB = 512 u32)
    __syncthreads();

    // xgate in / h out (in place, same address stream), leader rows only
    f16* xg = xh + (size_t)b * (HWN * RH) + s * 64 + r;
    float xnext = leader ? (float)xg[0] : 0.f;

    // poller: threads [64,512) each own one remote (slice,row) word
    const bool isPoller = (t >= 64);
    const int pi = (t - 64) >> 6;
    const int pp = pi + (pi >= s ? 1 : 0);
    const int pj = t & 63;

    const char* hb0 = (const char*)&hbuf[0][0];
    const int cbyte = c << 7;      // chunk byte offset

    for (int step = 0; step < HWN; step++) {
        const u32 tag  = (u32)(step + 1);
        const int nxt  = (int)(tag & 1);
        const char* hb = hb0 + ((step & 1) << 10);   // hbuf[step&1]

        u32* paddr = comm + ((size_t)(tag & 1) << 14) + ((size_t)b << 9)
                          + (pp << 6) + pj;
        // speculative pre-poll: overlaps matvec, absorbs partner skew
        u32 vpre = 0;
        if (isPoller)
            vpre = __hip_atomic_load(paddr, __ATOMIC_RELAXED, __HIP_MEMORY_SCOPE_AGENT);

        float xcur = xnext;
        if (leader && step + 1 < HWN)
            xnext = (float)xg[(size_t)(step + 1) * RH];

        // ---- matvec partial: 8 conflict-free b128 reads, 4 parallel chains
        float aA = 0.f, aB = 0.f, aC = 0.f, aD = 0.f;
        #define GRP(i, ACC, Wa, Wb, Wc, Wd)                                   \
        {   uint4 q = *(const uint4*)(hb + (cbyte | (((i) ^ c) << 4)));       \
            ACC = dot2acc(Wa, u2h(q.x), ACC);                                 \
            ACC = dot2acc(Wb, u2h(q.y), ACC);                                 \
            ACC = dot2acc(Wc, u2h(q.z), ACC);                                 \
            ACC = dot2acc(Wd, u2h(q.w), ACC); }
        GRP(0, aA, W00, W01, W02, W03)
        GRP(1, aB, W04, W05, W06, W07)
        GRP(2, aC, W08, W09, W10, W11)
        GRP(3, aD, W12, W13, W14, W15)
        GRP(4, aA, W16, W17, W18, W19)
        GRP(5, aB, W20, W21, W22, W23)
        GRP(6, aC, W24, W25, W26, W27)
        GRP(7, aD, W28, W29, W30, W31)
        #undef GRP
        float acc = (aA + aB) + (aC + aD);
        // ---- reduce across the 8 chunk lanes (in-wave)
        acc += __shfl_xor(acc, 1, 64);
        acc += __shfl_xor(acc, 2, 64);
        acc += __shfl_xor(acc, 4, 64);

        if (leader) {
            float h = tanhf(xcur + acc);
            f16 hf = (f16)h;
            u32 word = (tag << 16) | (u32)__builtin_bit_cast(unsigned short, hf);
            __hip_atomic_store(comm + ((size_t)(tag & 1) << 14) + ((size_t)b << 9)
                                    + (s << 6) + r,
                               word, __ATOMIC_RELAXED, __HIP_MEMORY_SCOPE_AGENT);
            hbuf[nxt][(s << 6) + r] = hf;
            xg[(size_t)step * RH] = hf;      // hs output (in place)
        }
        if (isPoller) {
            u32 v = vpre;
            if ((v >> 16) != tag) {
                u32 v2 = __hip_atomic_load(paddr, __ATOMIC_RELAXED, __HIP_MEMORY_SCOPE_AGENT);
                int guard = 0;
                while ((v >> 16) != tag && ++guard < (1 << 17)) {
                    v = v2;
                    v2 = __hip_atomic_load(paddr, __ATOMIC_RELAXED, __HIP_MEMORY_SCOPE_AGENT);
                }
            }
            hbuf[nxt][(pp << 6) + pj] =
                __builtin_bit_cast(f16, (unsigned short)(v & 0xFFFFu));
        }
        __syncthreads();
    }
}

// ------------------------------------------------------------------ launch
extern "C" void kernel_launch(void* const* d_in, const int* in_sizes, int n_in,
                              void* d_out, int out_size, void* d_ws, size_t ws_size,
                              hipStream_t stream) {
    const float* x     = (const float*)d_in[0];
    const float* gamma = (const float*)d_in[1];
    const float* beta  = (const float*)d_in[2];
    const float* w_in  = (const float*)d_in[3];
    const float* b_in  = (const float*)d_in[4];
    const float* w_ih  = (const float*)d_in[5];
    const float* b_ih  = (const float*)d_in[6];
    const float* w_hh  = (const float*)d_in[7];
    const float* b_hh  = (const float*)d_in[8];
    const float* w_out = (const float*)d_in[9];
    const float* b_out = (const float*)d_in[10];

    char* ws = (char*)d_ws;
    float* scale   = (float*)(ws + 0);         //   512 B
    float* shift   = (float*)(ws + 512);       //   512 B
    float* bihh    = (float*)(ws + 1024);      //  2 KB
    f16*   w_in_h  = (f16*)(ws + 4096);        // 64 KB
    f16*   w_ih_h  = (f16*)(ws + 69632);       // 256 KB
    f16*   w_out_h = (f16*)(ws + 331776);      // 128 KB
    u32*   wr      = (u32*)(ws + 462848);      // 512 KB packed W_hh
    u32*   comm    = (u32*)(ws + 987136);      // 128 KB h-exchange (2 par x 32 b x 512)
    f16*   xh      = (f16*)(ws + 1179648);     // 32 MB xgate, overwritten by hs
    f16*   A1      = (f16*)(ws + 34734080);    //  8 MB
    f16*   inp     = (f16*)(ws + 43122688);    // 16 MB (ends 59899904)

    bn_stats_kernel<<<128, 256, 0, stream>>>(x, gamma, beta, scale, shift);
    prep_w_kernel<<<1538, 256, 0, stream>>>(w_in, w_ih, w_out, w_hh, b_ih, b_hh,
                                            w_in_h, w_ih_h, w_out_h, wr, bihh, comm);
    prep_x_kernel<<<dim3(32, 4, 32), dim3(32, 8), 0, stream>>>(x, scale, shift, A1);
    gemm_kernel<0><<<dim3(128, 4), 256, 0, stream>>>(A1, w_in_h, b_in, (void*)inp, RIN, CC);
    gemm_kernel<1><<<dim3(128, 8), 256, 0, stream>>>(inp, w_ih_h, bihh, (void*)xh, RH, RIN);
    rnn_kernel<<<256, 512, 0, stream>>>(wr, xh, comm);
    gemm_kernel<2><<<dim3(128, 2), 256, 0, stream>>>(xh, w_out_h, b_out, d_out, OCN, RH);
}